// Round 3
// baseline (279.809 us; speedup 1.0000x reference)
//
#include <hip/hip_runtime.h>
#include <math.h>

// LDS: 4096 floats per wave (2 waves -> 32KB/block -> 5 blocks/CU).
// Carved per path:  B: 8 x 512 (prefetch-all-8, cnt4<=128)
//                   C: 4 x 1024 (ring-4, cnt4<=256)
//                   D: 2 x 2048 (2-deep, cnt4<=512; analysis: max cnt4 ~354)
//                   A: 8 x 512 (level-3 prefetch-all-8, cntS<=340<=384 words)
#define WAVE_F 4096
#define BPF    512
#define MAXB   2
#define MAXC4  4
#define MAXD   8
#define MAXK3  6

typedef __attribute__((address_space(3))) void lds_void;
typedef const __attribute__((address_space(1))) void g_void;

__device__ __forceinline__ void dma16(const float* g, float* l) {
  __builtin_amdgcn_global_load_lds((g_void*)g, (lds_void*)l, 16, 0, 0);
}
__device__ __forceinline__ void dma4(const float* g, float* l) {
  __builtin_amdgcn_global_load_lds((g_void*)g, (lds_void*)l, 4, 0, 0);
}
// Counted vmcnt wait, wave-uniform k (0..48). In-order retire => outstanding<=k
// implies everything older than the newest k ops has completed.
#define WC(N) case N: asm volatile("s_waitcnt vmcnt(" #N ")" ::: "memory"); break;
__device__ __forceinline__ void wait_vmcnt(int k) {
  switch (k) {
    WC(0) WC(1) WC(2) WC(3) WC(4) WC(5) WC(6) WC(7) WC(8) WC(9)
    WC(10) WC(11) WC(12) WC(13) WC(14) WC(15) WC(16) WC(17) WC(18) WC(19)
    WC(20) WC(21) WC(22) WC(23) WC(24) WC(25) WC(26) WC(27) WC(28) WC(29)
    WC(30) WC(31) WC(32) WC(33) WC(34) WC(35) WC(36) WC(37) WC(38) WC(39)
    WC(40) WC(41) WC(42) WC(43) WC(44) WC(45) WC(46) WC(47)
    default: asm volatile("s_waitcnt vmcnt(48)" ::: "memory"); break;
  }
}

// 49-lane bilinear 2x2x(2x2) gather + average + store; arrays are unroll-indexed (registers).
#define COMPUTE_STORE(TP, CC)                                                  \
  if (lane < 49) {                                                             \
    float acc = 0.0f;                                                          \
    _Pragma("unroll")                                                          \
    for (int sy = 0; sy < 2; ++sy) {                                           \
      _Pragma("unroll")                                                        \
      for (int sx = 0; sx < 2; ++sx) {                                         \
        const float w00 = (TP)[rT[sy] + Cc0[sx]];                              \
        const float w01 = (TP)[rT[sy] + Cc1[sx]];                              \
        const float w10 = (TP)[rB[sy] + Cc0[sx]];                              \
        const float w11 = (TP)[rB[sy] + Cc1[sx]];                              \
        const float bil = HY[sy] * (HX[sx] * w00 + LX[sx] * w01)               \
                        + LY[sy] * (HX[sx] * w10 + LX[sx] * w11);              \
        acc += (VY[sy] * VX[sx]) * bil;                                        \
      }                                                                        \
    }                                                                          \
    outp[(CC) * 49] = acc * 0.25f;                                             \
  }

__global__ __launch_bounds__(128) void pooler_kernel(
    const float* __restrict__ f0, const float* __restrict__ f1,
    const float* __restrict__ f2, const float* __restrict__ f3,
    const float* __restrict__ boxes, const int* __restrict__ bidx,
    float* __restrict__ out, int N)
{
  __shared__ __align__(16) float tile[2][WAVE_F];  // 32 KB/block
  const int tid  = threadIdx.x;
  const int wave = tid >> 6, lane = tid & 63;
  const int n    = blockIdx.y;
  if (n >= N) return;

  // ---- per-box meta (wave-uniform, recomputed by every lane) ----
  const float bx1 = boxes[4*n+0], by1 = boxes[4*n+1];
  const float bx2 = boxes[4*n+2], by2 = boxes[4*n+3];
  const float area = (bx2 - bx1 + 1.0f) * (by2 - by1 + 1.0f);
  const float s    = sqrtf(area);
  int lvl = (int)floorf(4.0f + log2f(s / 224.0f + 1e-6f));
  lvl = lvl < 2 ? 2 : (lvl > 5 ? 5 : lvl);
  const int li = lvl - 2;

  int H, W; const float* feat; float scale;
  switch (li) {
    case 0:  feat = f0; H = 200; W = 304; scale = 0.25f;    break;
    case 1:  feat = f1; H = 100; W = 152; scale = 0.125f;   break;
    case 2:  feat = f2; H = 50;  W = 76;  scale = 0.0625f;  break;
    default: feat = f3; H = 25;  W = 38;  scale = 0.03125f; break;
  }
  const int b = bidx[n];
  const float x1s = bx1 * scale, y1s = by1 * scale;
  const float roiw = fmaxf(bx2 * scale - x1s, 1.0f);
  const float roih = fmaxf(by2 * scale - y1s, 1.0f);
  const float binw = roiw / 7.0f, binh = roih / 7.0f;
  const float Hm1f = (float)(H - 1), Wm1f = (float)(W - 1);
  const int   Hm1  = H - 1,          Wm1  = W - 1;

  // ---- staged region bounds (samples monotone: first g=0.25, last g=6.75) ----
  const float yA = fminf(fmaxf(y1s + binh * 0.25f, 0.0f), Hm1f);
  const float yB = fminf(fmaxf(y1s + binh * 6.75f, 0.0f), Hm1f);
  const float xA = fminf(fmaxf(x1s + binw * 0.25f, 0.0f), Wm1f);
  const float xB = fminf(fmaxf(x1s + binw * 6.75f, 0.0f), Wm1f);
  const int y_lo  = (int)yA;
  const int y_hi  = min((int)yB + 1, Hm1);
  const int regH  = y_hi - y_lo + 1;
  const int x_lo4 = ((int)xA) & ~3;
  const int x_hi  = min((int)xB + 1, Wm1);
  const int row4  = ((x_hi - x_lo4 + 4) >> 2);
  const int regW4 = row4 << 2;

  // ---- per-lane bin parameters (channel-invariant; lanes 49..63 compute junk) ----
  const int bin = (lane < 49) ? lane : 0;
  const int ph = bin / 7, pw = bin - (bin / 7) * 7;
  int   rT[2], rB[2], Cc0[2], Cc1[2];
  float HY[2], LY[2], VY[2], HX[2], LX[2], VX[2];
#pragma unroll
  for (int t = 0; t < 2; ++t) {
    {
      const float g  = (float)ph + 0.25f + 0.5f * (float)t;
      const float Yf = y1s + binh * g;
      VY[t] = (Yf >= -1.0f && Yf <= (float)H) ? 1.0f : 0.0f;
      const float y = fminf(fmaxf(Yf, 0.0f), Hm1f);
      const int  y0 = (int)y;
      LY[t] = y - (float)y0;  HY[t] = 1.0f - LY[t];
      rT[t] = (y0 - y_lo) * regW4;
      rB[t] = (min(y0 + 1, Hm1) - y_lo) * regW4;
    }
    {
      const float g  = (float)pw + 0.25f + 0.5f * (float)t;
      const float Xf = x1s + binw * g;
      VX[t] = (Xf >= -1.0f && Xf <= (float)W) ? 1.0f : 0.0f;
      const float x = fminf(fmaxf(Xf, 0.0f), Wm1f);
      const int  x0 = (int)x;
      LX[t] = x - (float)x0;  HX[t] = 1.0f - LX[t];
      Cc0[t] = x0 - x_lo4;
      Cc1[t] = min(x0 + 1, Wm1) - x_lo4;
    }
  }

  // ---- pointers ----
  const size_t planeHW = (size_t)H * W;
  const int    cbase   = (blockIdx.x << 4) + (wave << 3);   // 8 channels per wave
  const float* plane0  = feat + ((size_t)(b * 256 + cbase)) * planeHW
                              + (size_t)y_lo * W;
  float*       outp    = out + ((size_t)n * 256 + cbase) * 49 + lane;
  float*       myt     = tile[wave];

  if (li != 3) {
    int cnt4 = regH * row4;
    if (cnt4 > 512) cnt4 = 512;   // safety (analysis: max ~354)

    // exact magic-divide by row4: valid since u<512, row4<=128 -> u*row4 < 65536
    const int Mrow = (int)(65536.0f / (float)row4) + 1;
    const int K = (cnt4 + 63) >> 6;   // DMA instrs per channel

    if (cnt4 <= 128) {
      // ======== path B: prefetch ALL 8 channels, one descending wait ladder ========
      int soff[MAXB];
#pragma unroll
      for (int i = 0; i < MAXB; ++i) {
        const int u = lane + (i << 6);
        if (u < cnt4) {
          const int r = (u * Mrow) >> 16;
          const int c = u - r * row4;
          soff[i] = r * W + x_lo4 + (c << 2);
        } else soff[i] = -1;
      }
#pragma unroll
      for (int p = 0; p < 8; ++p) {
        const float* pl = plane0 + (size_t)p * planeHW;
        float* bf = myt + p * BPF;
#pragma unroll
        for (int i = 0; i < MAXB; ++i)
          if (soff[i] >= 0) dma16(pl + soff[i], bf + (i << 8));
      }
#pragma unroll
      for (int cc = 0; cc < 8; ++cc) {
        // allowed outstanding: (7-cc) newer channels * K  +  cc older-than-them stores
        wait_vmcnt((7 - cc) * K + cc);
        const float* bufC = myt + cc * BPF;
        COMPUTE_STORE(bufC, cc)
      }
    } else if (cnt4 <= 256) {
      // ======== path C: ring-4 (4 x 1024 floats), prefetch distance 3 ========
      int soff[MAXC4];
#pragma unroll
      for (int i = 0; i < MAXC4; ++i) {
        const int u = lane + (i << 6);
        if (u < cnt4) {
          const int r = (u * Mrow) >> 16;
          const int c = u - r * row4;
          soff[i] = r * W + x_lo4 + (c << 2);
        } else soff[i] = -1;
      }
      // prologue: channels 0..2 -> ring slots 0..2
#pragma unroll
      for (int p = 0; p < 3; ++p) {
        const float* pl = plane0 + (size_t)p * planeHW;
        float* bf = myt + ((p & 3) << 10);
#pragma unroll
        for (int i = 0; i < MAXC4; ++i)
          if (soff[i] >= 0) dma16(pl + soff[i], bf + (i << 8));
      }
      for (int cc = 0; cc < 8; ++cc) {
        // slot (cc+3)&3 == (cc-1)&3 was read by compute(cc-1): drain its ds_reads
        asm volatile("s_waitcnt lgkmcnt(0)" ::: "memory");
        if (cc + 3 < 8) {
          const float* pl = plane0 + (size_t)(cc + 3) * planeHW;
          float* bf = myt + (((cc + 3) & 3) << 10);
#pragma unroll
          for (int i = 0; i < MAXC4; ++i)
            if (soff[i] >= 0) dma16(pl + soff[i], bf + (i << 8));
        }
        // newer ops: min(3,7-cc) channels * K DMAs + min(cc,3) stores
        const int nd = 7 - cc; 
        wait_vmcnt((nd > 3 ? 3 : nd) * K + (cc > 3 ? 3 : cc));
        const float* bufC = myt + ((cc & 3) << 10);
        COMPUTE_STORE(bufC, cc)
      }
    } else {
      // ======== path D: 2-deep (2 x 2048 floats) for rare elongated boxes ========
      int soff[MAXD];
#pragma unroll
      for (int i = 0; i < MAXD; ++i) {
        const int u = lane + (i << 6);
        if (u < cnt4) {
          const int r = (u * Mrow) >> 16;
          const int c = u - r * row4;
          soff[i] = r * W + x_lo4 + (c << 2);
        } else soff[i] = -1;
      }
      // prologue: channel 0 -> buffer 0
#pragma unroll
      for (int i = 0; i < MAXD; ++i)
        if (soff[i] >= 0) dma16(plane0 + soff[i], myt + (i << 8));

      for (int cc = 0; cc < 8; ++cc) {
        asm volatile("s_waitcnt lgkmcnt(0)" ::: "memory");
        if (cc + 1 < 8) {
          const float* pl = plane0 + (size_t)(cc + 1) * planeHW;
          float* bf = myt + (((cc + 1) & 1) << 11);
#pragma unroll
          for (int i = 0; i < MAXD; ++i)
            if (soff[i] >= 0) dma16(pl + soff[i], bf + (i << 8));
        }
        // newer ops: min(1,7-cc)*K DMAs + min(cc,1) stores (stores float free)
        wait_vmcnt((cc < 7 ? K : 0) + (cc > 0 ? 1 : 0));
        const float* bufC = myt + ((cc & 1) << 11);
        COMPUTE_STORE(bufC, cc)
      }
    }
  } else {
    // ======== path A: level-3 (W=38), word DMA, prefetch ALL 8 channels ========
    int cntS = regH * regW4;
    if (cntS > (MAXK3 << 6)) cntS = MAXK3 << 6;   // safety (analysis: <=340)
    const int MregW = (int)(65536.0f / (float)regW4) + 1;  // u<384, regW4<=44
    int soff3[MAXK3];
#pragma unroll
    for (int k = 0; k < MAXK3; ++k) {
      const int u = (k << 6) + lane;
      if (u < cntS) {
        const int r   = (u * MregW) >> 16;
        const int c   = u - r * regW4;
        const int col = x_lo4 + c;
        soff3[k] = (col <= Wm1) ? (r * W + col) : -1;   // junk cols masked, never read
      } else soff3[k] = -1;
    }
    const int K3 = (cntS + 63) >> 6;   // 1..6 (every k-group < cntS has >=1 active lane)

#pragma unroll
    for (int p = 0; p < 8; ++p) {
      const float* pl = plane0 + (size_t)p * planeHW;
      float* bf = myt + p * BPF;
#pragma unroll
      for (int k = 0; k < MAXK3; ++k)
        if (soff3[k] >= 0) dma4(pl + soff3[k], bf + (k << 6));
    }
#pragma unroll
    for (int cc = 0; cc < 8; ++cc) {
      wait_vmcnt((7 - cc) * K3 + cc);
      const float* bufC = myt + cc * BPF;
      COMPUTE_STORE(bufC, cc)
    }
  }
}

extern "C" void kernel_launch(void* const* d_in, const int* in_sizes, int n_in,
                              void* d_out, int out_size, void* d_ws, size_t ws_size,
                              hipStream_t stream) {
  const float* f0    = (const float*)d_in[0];
  const float* f1    = (const float*)d_in[1];
  const float* f2    = (const float*)d_in[2];
  const float* f3    = (const float*)d_in[3];
  const float* boxes = (const float*)d_in[4];
  const int*   bidx  = (const int*)d_in[5];
  const int N = in_sizes[5];                 // 1024 boxes
  dim3 grid(16, N);                          // 16 groups x (2 waves x 8 ch) = 256 channels
  pooler_kernel<<<grid, 128, 0, stream>>>(f0, f1, f2, f3, boxes, bidx,
                                          (float*)d_out, N);
}